// Round 8
// baseline (338.170 us; speedup 1.0000x reference)
//
#include <hip/hip_runtime.h>
#include <hip/hip_bf16.h>

#define N_NODES 50000
#define N_EDGES 800000
#define D_IN 128
#define D_HID 512
#define D_OUT 128
#define CAT_DIM 640   // D_IN + D_HID
#define CAP 64        // per-node edge-bucket capacity (Poisson(16): P(>=64) ~ 1e-20)

typedef __attribute__((ext_vector_type(8))) short short8;
typedef __attribute__((ext_vector_type(4))) float floatx4;

__device__ __forceinline__ unsigned short f2bf(float f) {
    unsigned u = __float_as_uint(f);
    unsigned r = u + 0x7fffu + ((u >> 16) & 1u);   // RNE
    return (unsigned short)(r >> 16);
}

// ================= prep_small: weight transposes + deg zero + dtype detect =

#define PS_FCW_BLOCKS 256   // 128*512 / 256
#define PS_W2_BLOCKS  320   // 640*128 / 256
#define PS_DEG_BLOCKS 196   // ceil(50000/256)
#define PS_TOTAL (PS_FCW_BLOCKS + PS_W2_BLOCKS + PS_DEG_BLOCKS + 1)

__global__ void prep_kernel(const float* __restrict__ fcW, const float* __restrict__ Wm,
                            const int* __restrict__ adj,
                            unsigned short* __restrict__ fcwT,
                            unsigned short* __restrict__ WT,
                            int* __restrict__ deg, int* __restrict__ flag) {
    int b = blockIdx.x;
    int tid = threadIdx.x;
    if (b < PS_FCW_BLOCKS) {
        int idx = b * 256 + tid;               // 128*512
        int k = idx >> 9;
        int n = idx & (D_HID - 1);
        fcwT[n * D_IN + k] = f2bf(fcW[idx]);
        return;
    }
    b -= PS_FCW_BLOCKS;
    if (b < PS_W2_BLOCKS) {
        int idx = b * 256 + tid;               // 640*128
        int k = idx >> 7;
        int n = idx & (D_OUT - 1);
        WT[n * CAT_DIM + k] = f2bf(Wm[idx]);
        return;
    }
    b -= PS_W2_BLOCKS;
    if (b < PS_DEG_BLOCKS) {
        int idx = b * 256 + tid;
        if (idx < N_NODES) deg[idx] = 0;
        return;
    }
    // detect (wave 0): int64 high words all zero (node ids < 2^31)
    if (tid < 64) {
        int v = adj[2 * tid + 1];
        unsigned long long m = __ballot(v != 0);
        if (tid == 0) *flag = (m == 0ULL) ? 2 : 1;   // 2 => int64 stride
    }
}

// ================= hist (device fn, fused into mid kernel) =================

__device__ __forceinline__ void hist_edges(const int* __restrict__ adj, int s, int e0,
                                           int* __restrict__ deg, int* __restrict__ edge_list) {
    int src0, src1, trg0, trg1;
    if (s == 2) {   // int64: edges e0,e0+1 -> adj dwords [2e0 .. 2e0+3], coalesced
        int4 vs = *(const int4*)(adj + 2 * (size_t)e0);
        int4 vt = *(const int4*)(adj + 2 * ((size_t)N_EDGES + e0));
        src0 = vs.x; src1 = vs.z;
        trg0 = vt.x; trg1 = vt.z;
    } else {        // int32
        int2 vs = *(const int2*)(adj + e0);
        int2 vt = *(const int2*)(adj + N_EDGES + e0);
        src0 = vs.x; src1 = vs.y;
        trg0 = vt.x; trg1 = vt.y;
    }
    int p0 = atomicAdd(&deg[src0], 1);
    if (p0 < CAP) edge_list[src0 * CAP + p0] = trg0;
    int p1 = atomicAdd(&deg[src1], 1);
    if (p1 < CAP) edge_list[src1 * CAP + p1] = trg1;
}

// ================= fused mid: hist blocks + GEMM1 blocks ===================
// GEMM1: BM=64, K=128 staged ONCE from fp32 X (cast in staging); block loops
// all 4 N-tiles of fcwT with A resident in LDS. 2x2 waves, 32x64 wave tiles.

#define HIST_VB   1563   // ceil((N_EDGES/2)/256)
#define GEMM1_MT   782   // ceil(50000/64)
#define LPAD 8

__global__ __launch_bounds__(256)
void mid_kernel(const int* __restrict__ adj, const int* __restrict__ flag,
                int* __restrict__ deg, int* __restrict__ edge_list,
                const float* __restrict__ X,
                const unsigned short* __restrict__ fcwT,
                const float* __restrict__ fcb,
                unsigned short* __restrict__ F) {
    if (blockIdx.x < HIST_VB) {
        int e0 = (blockIdx.x * 256 + threadIdx.x) * 2;
        if (e0 < N_EDGES) hist_edges(adj, flag[0], e0, deg, edge_list);
        return;
    }
    __shared__ unsigned short As[64][D_IN + LPAD];
    __shared__ unsigned short Bs[128][D_IN + LPAD];
    int tid = threadIdx.x;
    int lane = tid & 63, w = tid >> 6;
    int wm = (w >> 1) * 32, wn = (w & 1) * 64;
    int q = lane >> 4, l16 = lane & 15;
    int bm = (blockIdx.x - HIST_VB) * 64;

    // stage A once: 64 rows x 128 cols from X fp32, cast to bf16
    {
        int ra = tid >> 2;            // 0..63
        int ca = (tid & 3) * 32;      // 4 col groups of 32
        int gr = bm + ra;
        #pragma unroll
        for (int p = 0; p < 8; ++p) {
            float4 v = make_float4(0.f, 0.f, 0.f, 0.f);
            if (gr < N_NODES) v = *(const float4*)(X + (size_t)gr * D_IN + ca + p * 4);
            unsigned short o[4] = { f2bf(v.x), f2bf(v.y), f2bf(v.z), f2bf(v.w) };
            *(unsigned long long*)(&As[ra][ca + p * 4]) = *(unsigned long long*)o;
        }
    }

    int rb = tid >> 1;                // 0..127
    int cb = (tid & 1) * 64;
    for (int nt = 0; nt < 4; ++nt) {
        if (nt) __syncthreads();      // previous compute done before Bs overwrite
        {
            const unsigned short* bp = fcwT + (size_t)(nt * 128 + rb) * D_IN + cb;
            #pragma unroll
            for (int p = 0; p < 8; ++p)
                *(uint4*)(&Bs[rb][cb + p * 8]) = *(const uint4*)(bp + p * 8);
        }
        __syncthreads();              // staging (and As on nt=0) visible

        floatx4 acc[2][4] = {};
        #pragma unroll
        for (int ks = 0; ks < 4; ++ks) {
            short8 af[2], bf[4];
            #pragma unroll
            for (int mi = 0; mi < 2; ++mi)
                af[mi] = *(const short8*)(&As[wm + mi * 16 + l16][ks * 32 + q * 8]);
            #pragma unroll
            for (int ni = 0; ni < 4; ++ni)
                bf[ni] = *(const short8*)(&Bs[wn + ni * 16 + l16][ks * 32 + q * 8]);
            #pragma unroll
            for (int mi = 0; mi < 2; ++mi)
                #pragma unroll
                for (int ni = 0; ni < 4; ++ni)
                    acc[mi][ni] = __builtin_amdgcn_mfma_f32_16x16x32_bf16(af[mi], bf[ni], acc[mi][ni], 0, 0, 0);
        }

        #pragma unroll
        for (int mi = 0; mi < 2; ++mi) {
            #pragma unroll
            for (int ni = 0; ni < 4; ++ni) {
                #pragma unroll
                for (int r = 0; r < 4; ++r) {
                    int row = bm + wm + mi * 16 + q * 4 + r;
                    int col = nt * 128 + wn + ni * 16 + l16;
                    if (row < N_NODES) {
                        float v = fmaxf(acc[mi][ni][r] + fcb[col], 0.0f);
                        F[(size_t)row * D_HID + col] = f2bf(v);
                    }
                }
            }
        }
    }
}

// ================= aggregate: wave per node (proven form; dense A2 out) ====

__device__ __forceinline__ void fmax_bf16x8(float* acc, const uint4& p) {
    const unsigned* a = (const unsigned*)&p;
    #pragma unroll
    for (int j = 0; j < 4; ++j) {
        unsigned u = a[j];
        acc[2 * j]     = fmaxf(acc[2 * j],     __uint_as_float(u << 16));
        acc[2 * j + 1] = fmaxf(acc[2 * j + 1], __uint_as_float(u & 0xffff0000u));
    }
}

__global__ __launch_bounds__(256)
void aggregate_kernel(const unsigned short* __restrict__ F,
                      const int* __restrict__ deg,
                      const int* __restrict__ edge_list,
                      unsigned short* __restrict__ A2) {
    int gw = (blockIdx.x * 256 + threadIdx.x) >> 6;
    if (gw >= N_NODES) return;
    int lane = threadIdx.x & 63;
    int d = deg[gw];
    d = d < CAP ? d : CAP;
    const int* el = edge_list + gw * CAP;
    float acc[8] = {0.f, 0.f, 0.f, 0.f, 0.f, 0.f, 0.f, 0.f};
    int i = 0;
    for (; i + 2 <= d; i += 2) {
        int t0 = el[i], t1 = el[i + 1];
        uint4 p0 = *(const uint4*)(F + (size_t)t0 * D_HID + lane * 8);
        uint4 p1 = *(const uint4*)(F + (size_t)t1 * D_HID + lane * 8);
        fmax_bf16x8(acc, p0);
        fmax_bf16x8(acc, p1);
    }
    if (i < d) {
        uint4 p0 = *(const uint4*)(F + (size_t)el[i] * D_HID + lane * 8);
        fmax_bf16x8(acc, p0);
    }
    unsigned out[4];
    #pragma unroll
    for (int j = 0; j < 4; ++j) {
        unsigned lo = __float_as_uint(acc[2 * j]) >> 16;          // exact: maxima of bf16 values
        unsigned hi = __float_as_uint(acc[2 * j + 1]) & 0xffff0000u;
        out[j] = lo | hi;
    }
    *(uint4*)(A2 + (size_t)gw * D_HID + lane * 8) = *(uint4*)out;
}

// ================= GEMM2: BM=64, BN=128, BK=128, 5 K-iters =================
// iter 0: A from X fp32 (cast in staging); iters 1..4: A from dense A2 bf16.

__global__ __launch_bounds__(256)
void gemm2_kernel(const float* __restrict__ X,
                  const unsigned short* __restrict__ A2,
                  const unsigned short* __restrict__ WT,
                  float* __restrict__ out) {
    __shared__ unsigned short As[64][128 + LPAD];
    __shared__ unsigned short Bs[128][128 + LPAD];
    int tid = threadIdx.x;
    int lane = tid & 63, w = tid >> 6;
    int wm = (w >> 1) * 32, wn = (w & 1) * 64;
    int q = lane >> 4, l16 = lane & 15;
    int bm = blockIdx.x * 64;

    floatx4 acc[2][4] = {};
    int ra = tid >> 2;            // 0..63
    int ca = (tid & 3) * 32;
    int rb = tid >> 1;            // 0..127
    int cb = (tid & 1) * 64;

    #pragma unroll
    for (int it = 0; it < 5; ++it) {
        if (it) __syncthreads();
        int gr = bm + ra;
        if (it == 0) {            // A from X fp32
            #pragma unroll
            for (int p = 0; p < 8; ++p) {
                float4 v = make_float4(0.f, 0.f, 0.f, 0.f);
                if (gr < N_NODES) v = *(const float4*)(X + (size_t)gr * D_IN + ca + p * 4);
                unsigned short o[4] = { f2bf(v.x), f2bf(v.y), f2bf(v.z), f2bf(v.w) };
                *(unsigned long long*)(&As[ra][ca + p * 4]) = *(unsigned long long*)o;
            }
        } else {                  // A from A2 bf16, cols (it-1)*128..+128
            const unsigned short* ap = A2 + (size_t)gr * D_HID + (it - 1) * 128 + ca;
            #pragma unroll
            for (int p = 0; p < 4; ++p) {
                uint4 v = make_uint4(0u, 0u, 0u, 0u);
                if (gr < N_NODES) v = *(const uint4*)(ap + p * 8);
                *(uint4*)(&As[ra][ca + p * 8]) = v;
            }
        }
        {
            const unsigned short* bp = WT + (size_t)rb * CAT_DIM + it * 128 + cb;
            #pragma unroll
            for (int p = 0; p < 8; ++p)
                *(uint4*)(&Bs[rb][cb + p * 8]) = *(const uint4*)(bp + p * 8);
        }
        __syncthreads();

        #pragma unroll
        for (int ks = 0; ks < 4; ++ks) {
            short8 af[2], bf[4];
            #pragma unroll
            for (int mi = 0; mi < 2; ++mi)
                af[mi] = *(const short8*)(&As[wm + mi * 16 + l16][ks * 32 + q * 8]);
            #pragma unroll
            for (int ni = 0; ni < 4; ++ni)
                bf[ni] = *(const short8*)(&Bs[wn + ni * 16 + l16][ks * 32 + q * 8]);
            #pragma unroll
            for (int mi = 0; mi < 2; ++mi)
                #pragma unroll
                for (int ni = 0; ni < 4; ++ni)
                    acc[mi][ni] = __builtin_amdgcn_mfma_f32_16x16x32_bf16(af[mi], bf[ni], acc[mi][ni], 0, 0, 0);
        }
    }

    #pragma unroll
    for (int mi = 0; mi < 2; ++mi) {
        #pragma unroll
        for (int ni = 0; ni < 4; ++ni) {
            #pragma unroll
            for (int r = 0; r < 4; ++r) {
                int row = bm + wm + mi * 16 + q * 4 + r;
                int col = wn + ni * 16 + l16;
                if (row < N_NODES)
                    out[(size_t)row * D_OUT + col] = acc[mi][ni][r];
            }
        }
    }
}

// ================= host launch =============================================

extern "C" void kernel_launch(void* const* d_in, const int* in_sizes, int n_in,
                              void* d_out, int out_size, void* d_ws, size_t ws_size,
                              hipStream_t stream) {
    const float* X    = (const float*)d_in[0];
    const float* fc_w = (const float*)d_in[1];
    const float* fc_b = (const float*)d_in[2];
    const float* Wm   = (const float*)d_in[3];
    const int*   adj  = (const int*)d_in[4];
    float* outp = (float*)d_out;

    char* ws = (char*)d_ws;
    size_t off = 0;
    auto alloc = [&](size_t bytes) -> void* {
        void* p = ws + off;
        off = (off + bytes + 255) & ~(size_t)255;
        return p;
    };
    unsigned short* F    = (unsigned short*)alloc((size_t)N_NODES * D_HID * 2);
    unsigned short* A2   = (unsigned short*)alloc((size_t)N_NODES * D_HID * 2);
    unsigned short* fcwT = (unsigned short*)alloc((size_t)D_HID * D_IN * 2);
    unsigned short* WT   = (unsigned short*)alloc((size_t)D_OUT * CAT_DIM * 2);
    int* deg       = (int*)alloc((size_t)N_NODES * 4);
    int* edge_list = (int*)alloc((size_t)N_NODES * CAP * 4);
    int* flag      = (int*)alloc(256);

    prep_kernel<<<PS_TOTAL, 256, 0, stream>>>(fc_w, Wm, adj, fcwT, WT, deg, flag);
    mid_kernel<<<HIST_VB + GEMM1_MT, 256, 0, stream>>>(adj, flag, deg, edge_list,
                                                       X, fcwT, fc_b, F);
    aggregate_kernel<<<(N_NODES * 64) / 256, 256, 0, stream>>>(F, deg, edge_list, A2);
    gemm2_kernel<<<GEMM1_MT, 256, 0, stream>>>(X, A2, WT, outp);
}